// Round 11
// baseline (524.496 us; speedup 1.0000x reference)
//
#include <hip/hip_runtime.h>

static constexpr int Nn  = 100000;
static constexpr int Ne  = 1600000;
static constexpr int Gg  = 2048;
static constexpr int Fin = 22;
static constexpr float EPSf = 1e-5f;
static constexpr int NBLK = (Nn + 255) / 256;   // 391 scan blocks

// ---------------- init: zero cnt + stats ----------------
__global__ void k_init(int* cnt, double* stats) {
    int i = blockIdx.x * blockDim.x + threadIdx.x;
    int stride = gridDim.x * blockDim.x;
    for (int j = i; j < Nn; j += stride) cnt[j] = 0;
    for (int j = i; j < 256; j += stride) stats[j] = 0.0;   // stats1+stats2
}

// ---------------- in-degree histogram (int atomics) ----------------
__global__ void k_count(const int* __restrict__ dst, int* cnt) {
    int e = blockIdx.x * blockDim.x + threadIdx.x;
    if (e < Ne) atomicAdd(&cnt[dst[e]], 1);
}

// ---------------- scan pass 1: per-block exclusive scan ----------------
__global__ __launch_bounds__(256) void k_scan1(const int* __restrict__ cnt,
                                               int* row_ptr, int* bsum) {
    __shared__ int sh[256];
    int t = threadIdx.x, b = blockIdx.x;
    int i = b * 256 + t;
    int v = (i < Nn) ? cnt[i] : 0;
    sh[t] = v;
    __syncthreads();
    for (int off = 1; off < 256; off <<= 1) {
        int a = (t >= off) ? sh[t - off] : 0;
        __syncthreads();
        sh[t] += a;
        __syncthreads();
    }
    if (i < Nn) row_ptr[i] = sh[t] - v;     // exclusive within block
    if (t == 255) bsum[b] = sh[255];
}

// ---------------- scan pass 2: scan the 391 block sums ----------------
__global__ __launch_bounds__(512) void k_scan2(int* bsum) {
    __shared__ int sh[512];
    int t = threadIdx.x;
    int v = (t < NBLK) ? bsum[t] : 0;
    sh[t] = v;
    __syncthreads();
    for (int off = 1; off < 512; off <<= 1) {
        int a = (t >= off) ? sh[t - off] : 0;
        __syncthreads();
        sh[t] += a;
        __syncthreads();
    }
    if (t < NBLK) bsum[t] = sh[t] - v;      // exclusive
}

// ---------------- scan pass 3: add offsets, cursor copy, dinv ----------------
__global__ __launch_bounds__(256) void k_scan3(const int* __restrict__ cnt,
                                               const int* __restrict__ bsum,
                                               int* row_ptr, int* cursor, float* dinv) {
    int i = blockIdx.x * blockDim.x + threadIdx.x;
    if (i >= Nn) return;
    int r = row_ptr[i] + bsum[i >> 8];
    row_ptr[i] = r;
    cursor[i] = r;
    dinv[i] = rsqrtf(1.0f + (float)cnt[i]);
    if (i == 0) row_ptr[Nn] = Ne;
}

// ---------------- pad + pre-scale: xp[n] = x[n] * dinv[n], 22->24 floats ----------------
__global__ void k_pad(const float* __restrict__ x, const float* __restrict__ dinv,
                      float* __restrict__ xp) {
    int idx = blockIdx.x * blockDim.x + threadIdx.x;   // Nn*6 float4s
    if (idx >= Nn * 6) return;
    int n = idx / 6, q = idx - n * 6;
    float di = dinv[n];
    float4 v;
    int f0 = q * 4;
    const float* xr = x + n * Fin;
    v.x = (f0 + 0 < Fin) ? xr[f0 + 0] * di : 0.f;
    v.y = (f0 + 1 < Fin) ? xr[f0 + 1] * di : 0.f;
    v.z = (f0 + 2 < Fin) ? xr[f0 + 2] * di : 0.f;
    v.w = (f0 + 3 < Fin) ? xr[f0 + 3] * di : 0.f;
    ((float4*)xp)[idx] = v;
}

// ---------------- CSR fill: src-only, single 4B store per edge ----------------
__global__ void k_fill(const int* __restrict__ src, const int* __restrict__ dst,
                       int* cursor, int* __restrict__ csr_src) {
    int e = blockIdx.x * blockDim.x + threadIdx.x;
    if (e >= Ne) return;
    int pos = atomicAdd(&cursor[dst[e]], 1);
    csr_src[pos] = src[e];
}

// ---------------- gather1: aggx[n] = dinv[n] * (xp'[n] + sum_e xp'[src])  (24 floats) ----------------
__global__ __launch_bounds__(256) void k_gather1(const int* __restrict__ row_ptr,
                                                 const int* __restrict__ csr_src,
                                                 const float* __restrict__ dinv,
                                                 const float* __restrict__ xp,
                                                 float* __restrict__ outp) {
    int idx = blockIdx.x * blockDim.x + threadIdx.x;   // Nn*6 threads
    if (idx >= Nn * 6) return;
    int n = idx / 6, q = idx - n * 6;
    const float4* h4 = (const float4*)xp;
    float di = dinv[n];
    float4 a0 = h4[n * 6 + q];     // self term (xp already scaled by dinv[n])
    float4 a1 = make_float4(0.f, 0.f, 0.f, 0.f);
    float4 a2 = make_float4(0.f, 0.f, 0.f, 0.f);
    float4 a3 = make_float4(0.f, 0.f, 0.f, 0.f);
    int e = row_ptr[n], e1 = row_ptr[n + 1];
    for (; e + 3 < e1; e += 4) {
        int s0 = csr_src[e], s1 = csr_src[e + 1], s2 = csr_src[e + 2], s3 = csr_src[e + 3];
        float4 v0 = h4[s0 * 6 + q];
        float4 v1 = h4[s1 * 6 + q];
        float4 v2 = h4[s2 * 6 + q];
        float4 v3 = h4[s3 * 6 + q];
        a0.x += v0.x; a0.y += v0.y; a0.z += v0.z; a0.w += v0.w;
        a1.x += v1.x; a1.y += v1.y; a1.z += v1.z; a1.w += v1.w;
        a2.x += v2.x; a2.y += v2.y; a2.z += v2.z; a2.w += v2.w;
        a3.x += v3.x; a3.y += v3.y; a3.z += v3.z; a3.w += v3.w;
    }
    for (; e < e1; e++) {
        int s = csr_src[e];
        float4 v = h4[s * 6 + q];
        a0.x += v.x; a0.y += v.y; a0.z += v.z; a0.w += v.w;
    }
    float4 r;
    r.x = (a0.x + a1.x + a2.x + a3.x) * di;
    r.y = (a0.y + a1.y + a2.y + a3.y) * di;
    r.z = (a0.z + a1.z + a2.z + a3.z) * di;
    r.w = (a0.w + a1.w + a2.w + a3.w) * di;
    ((float4*)outp)[n * 6 + q] = r;
}

// ---------------- GEMM1: aggx[N,24(22)] @ W1[64,22]^T + b1 -> h1[N,64] ----------------
__global__ __launch_bounds__(256) void k_gemm1(const float* __restrict__ aggx,
                                               const float* __restrict__ W1,
                                               const float* __restrict__ b1,
                                               float* __restrict__ out) {
    __shared__ float Wl[64 * 23];
    __shared__ float Xl[4][24];
    int tid = threadIdx.x;
    for (int i = tid; i < 64 * Fin; i += 256) {
        int o = i / Fin, k = i % Fin;
        Wl[o * 23 + k] = W1[i];
    }
    int f = tid & 63, ln = tid >> 6;
    float bf = b1[f];
    for (int base = blockIdx.x * 4; base < Nn; base += gridDim.x * 4) {
        __syncthreads();
        if (tid < 24) {
            int r = tid / 6, q = tid - (tid / 6) * 6;
            if (base + r < Nn)
                *((float4*)&Xl[r][q * 4]) = ((const float4*)aggx)[(base + r) * 6 + q];
        }
        __syncthreads();
        int n = base + ln;
        if (n < Nn) {
            float s = bf;
            #pragma unroll
            for (int k = 0; k < Fin; k++) s += Xl[ln][k] * Wl[f * 23 + k];
            out[n * 64 + f] = s;
        }
    }
}

// ---------------- BN stats: per-feature sum & sumsq (double accum) ----------------
__global__ __launch_bounds__(256) void k_bnstats(const float* __restrict__ a, double* stats) {
    __shared__ float ssum[256], ssq[256];
    int tid = threadIdx.x;
    int f = tid & 63, ln = tid >> 6;
    float s = 0.f, q = 0.f;
    for (int n = blockIdx.x * 4 + ln; n < Nn; n += gridDim.x * 4) {
        float v = a[n * 64 + f];
        s += v;
        q += v * v;
    }
    ssum[tid] = s; ssq[tid] = q;
    __syncthreads();
    if (tid < 64) {
        s = ssum[tid] + ssum[tid + 64] + ssum[tid + 128] + ssum[tid + 192];
        q = ssq[tid] + ssq[tid + 64] + ssq[tid + 128] + ssq[tid + 192];
        atomicAdd(&stats[f], (double)s);
        atomicAdd(&stats[64 + f], (double)q);
    }
}

// ---------------- GEMM2, fused BN1+ReLU on load, epilogue * dinv[n] ----------------
__global__ __launch_bounds__(256) void k_gemm2(const float* __restrict__ xin,
                                               const float* __restrict__ W2,
                                               const double* __restrict__ stats,
                                               const float* __restrict__ g,
                                               const float* __restrict__ be,
                                               const float* __restrict__ dinv,
                                               float* __restrict__ out) {
    __shared__ float Wl[64 * 65];
    __shared__ float Xl[4][64];
    int tid = threadIdx.x;
    for (int i = tid; i < 64 * 64; i += 256) {
        int o = i >> 6, k = i & 63;
        Wl[o * 65 + k] = W2[i];
    }
    int f = tid & 63, ln = tid >> 6;
    double mu = stats[f] / (double)Nn;
    double var = stats[64 + f] / (double)Nn - mu * mu;
    float sc = rsqrtf((float)var + EPSf) * g[f];
    float muf = (float)mu;
    float bef = be[f];
    for (int base = blockIdx.x * 4; base < Nn; base += gridDim.x * 4) {
        __syncthreads();
        int n = base + ln;
        if (n < Nn) {
            float v = (xin[n * 64 + f] - muf) * sc + bef;
            Xl[ln][f] = v > 0.f ? v : 0.f;
        }
        __syncthreads();
        if (n < Nn) {
            float s = 0.f;
            #pragma unroll
            for (int k = 0; k < 64; k++) s += Xl[ln][k] * Wl[f * 65 + k];
            out[n * 64 + f] = s * dinv[n];   // pre-scale row for src-only gather
        }
    }
}

// ---------------- gather2: out[n] = dinv[n]*(h'[n] + sum_e h'[src]) + b  (64 floats) ----------------
__global__ __launch_bounds__(256) void k_gather2(const int* __restrict__ row_ptr,
                                                 const int* __restrict__ csr_src,
                                                 const float* __restrict__ dinv,
                                                 const float* __restrict__ h,
                                                 const float* __restrict__ bias,
                                                 float* __restrict__ out) {
    int idx = blockIdx.x * blockDim.x + threadIdx.x;   // Nn*16 threads
    if (idx >= Nn * 16) return;
    int n = idx >> 4, q = idx & 15;
    const float4* h4 = (const float4*)h;
    float di = dinv[n];
    float4 bv = ((const float4*)bias)[q];
    float4 a0 = h4[n * 16 + q];    // self term (h already scaled by dinv[n])
    float4 a1 = make_float4(0.f, 0.f, 0.f, 0.f);
    float4 a2 = make_float4(0.f, 0.f, 0.f, 0.f);
    float4 a3 = make_float4(0.f, 0.f, 0.f, 0.f);
    int e = row_ptr[n], e1 = row_ptr[n + 1];
    for (; e + 3 < e1; e += 4) {
        int s0 = csr_src[e], s1 = csr_src[e + 1], s2 = csr_src[e + 2], s3 = csr_src[e + 3];
        float4 v0 = h4[s0 * 16 + q];
        float4 v1 = h4[s1 * 16 + q];
        float4 v2 = h4[s2 * 16 + q];
        float4 v3 = h4[s3 * 16 + q];
        a0.x += v0.x; a0.y += v0.y; a0.z += v0.z; a0.w += v0.w;
        a1.x += v1.x; a1.y += v1.y; a1.z += v1.z; a1.w += v1.w;
        a2.x += v2.x; a2.y += v2.y; a2.z += v2.z; a2.w += v2.w;
        a3.x += v3.x; a3.y += v3.y; a3.z += v3.z; a3.w += v3.w;
    }
    for (; e < e1; e++) {
        int s = csr_src[e];
        float4 v = h4[s * 16 + q];
        a0.x += v.x; a0.y += v.y; a0.z += v.z; a0.w += v.w;
    }
    float4 r;
    r.x = (a0.x + a1.x + a2.x + a3.x) * di + bv.x;
    r.y = (a0.y + a1.y + a2.y + a3.y) * di + bv.y;
    r.z = (a0.z + a1.z + a2.z + a3.z) * di + bv.z;
    r.w = (a0.w + a1.w + a2.w + a3.w) * di + bv.w;
    ((float4*)out)[n * 16 + q] = r;
}

// ---------------- pool + BN2 + ReLU + MLP, one block (64 thr) per graph ----------------
__global__ __launch_bounds__(64) void k_poolmlp(const float* __restrict__ a,
                                                const int* __restrict__ batch,
                                                const double* __restrict__ stats,
                                                const float* __restrict__ g,
                                                const float* __restrict__ be,
                                                const float* __restrict__ fcw1,
                                                const float* __restrict__ fcb1,
                                                const float* __restrict__ fcw2,
                                                const float* __restrict__ fcb2,
                                                float* __restrict__ out) {
    __shared__ float p[64];
    int gidx = blockIdx.x;
    int tid = threadIdx.x;   // feature
    int lo = 0, hi = Nn;
    while (lo < hi) { int m = (lo + hi) >> 1; if (batch[m] < gidx) lo = m + 1; else hi = m; }
    int start = lo;
    hi = Nn;
    while (lo < hi) { int m = (lo + hi) >> 1; if (batch[m] < gidx + 1) lo = m + 1; else hi = m; }
    int end = lo;
    double mu = stats[tid] / (double)Nn;
    double var = stats[64 + tid] / (double)Nn - mu * mu;
    float sc = rsqrtf((float)var + EPSf) * g[tid];
    float muf = (float)mu;
    float bef = be[tid];
    float s = 0.f;
    for (int n = start; n < end; n++) {
        float v = (a[n * 64 + tid] - muf) * sc + bef;
        s += v > 0.f ? v : 0.f;
    }
    int cnt = end - start;
    float c = cnt < 1 ? 1.f : (float)cnt;
    p[tid] = s / c;
    __syncthreads();
    float w = 0.f;
    if (tid < 32) {
        float z = fcb1[tid];
        #pragma unroll
        for (int k = 0; k < 64; k++) z += p[k] * fcw1[tid * 64 + k];
        z = z > 0.f ? z : 0.f;
        w = z * fcw2[tid];
    }
    for (int off = 16; off; off >>= 1) w += __shfl_down(w, off);
    if (tid == 0) out[gidx] = w + fcb2[0];
}

extern "C" void kernel_launch(void* const* d_in, const int* in_sizes, int n_in,
                              void* d_out, int out_size, void* d_ws, size_t ws_size,
                              hipStream_t stream) {
    const float* x    = (const float*)d_in[0];
    const int* ei     = (const int*)d_in[1];
    const int* src    = ei;
    const int* dst    = ei + Ne;
    const int* batch  = (const int*)d_in[2];
    const float* W1   = (const float*)d_in[3];
    const float* b1   = (const float*)d_in[4];
    const float* g1   = (const float*)d_in[5];
    const float* be1  = (const float*)d_in[6];
    const float* W2   = (const float*)d_in[7];
    const float* b2   = (const float*)d_in[8];
    const float* g2   = (const float*)d_in[9];
    const float* be2  = (const float*)d_in[10];
    const float* fcw1 = (const float*)d_in[11];
    const float* fcb1 = (const float*)d_in[12];
    const float* fcw2 = (const float*)d_in[13];
    const float* fcb2 = (const float*)d_in[14];
    float* out = (float*)d_out;

    // workspace layout (8B-aligned blocks first)
    double* stats1  = (double*)d_ws;             // 128
    double* stats2  = stats1 + 128;              // 128
    int*    csr_src = (int*)(stats2 + 128);      // Ne (src-only CSR)
    float*  bufA    = (float*)(csr_src + Ne);    // N*64: xp -> h1 -> agg2
    float*  bufB    = bufA + Nn * 64;            // N*64: aggx -> h2'
    float*  dinv    = bufB + Nn * 64;            // N
    int*    cnt     = (int*)(dinv + Nn);         // N
    int*    row_ptr = cnt + Nn;                  // N+1
    int*    cursor  = row_ptr + Nn + 1;          // N
    int*    bsum    = cursor + Nn;               // 512

    // ---- degree + CSR layout ----
    k_init<<<512, 256, 0, stream>>>(cnt, stats1);
    k_count<<<(Ne + 255) / 256, 256, 0, stream>>>(dst, cnt);
    k_scan1<<<NBLK, 256, 0, stream>>>(cnt, row_ptr, bsum);
    k_scan2<<<1, 512, 0, stream>>>(bsum);
    k_scan3<<<NBLK, 256, 0, stream>>>(cnt, bsum, row_ptr, cursor, dinv);

    // ---- pre-scaled pad + src-only CSR fill ----
    k_pad<<<(Nn * 6 + 255) / 256, 256, 0, stream>>>(x, dinv, bufA);
    k_fill<<<(Ne + 255) / 256, 256, 0, stream>>>(src, dst, cursor, csr_src);

    // ---- layer 1: gather pre-scaled x (24f rows), then GEMM ----
    k_gather1<<<(Nn * 6 + 255) / 256, 256, 0, stream>>>(row_ptr, csr_src, dinv, bufA, bufB);
    k_gemm1<<<1024, 256, 0, stream>>>(bufB, W1, b1, bufA);
    k_bnstats<<<512, 256, 0, stream>>>(bufA, stats1);

    // ---- layer 2: GEMM (BN1+ReLU fused, *dinv epilogue), then gather ----
    k_gemm2<<<2048, 256, 0, stream>>>(bufA, W2, stats1, g1, be1, dinv, bufB);
    k_gather2<<<(Nn * 16 + 255) / 256, 256, 0, stream>>>(row_ptr, csr_src, dinv, bufB, b2, bufA);
    k_bnstats<<<512, 256, 0, stream>>>(bufA, stats2);

    // ---- pool + BN2 + ReLU + MLP ----
    k_poolmlp<<<Gg, 64, 0, stream>>>(bufA, batch, stats2, g2, be2,
                                     fcw1, fcb1, fcw2, fcb2, out);
}

// Round 14
// 402.390 us; speedup vs baseline: 1.3035x; 1.3035x over previous
//
#include <hip/hip_runtime.h>

static constexpr int Nn  = 100000;
static constexpr int Ne  = 1600000;
static constexpr int Gg  = 2048;
static constexpr int Fin = 22;
static constexpr float EPSf = 1e-5f;

static constexpr int NP   = 250;              // partition workgroups
static constexpr int CH   = Ne / NP;          // 6400 edges per chunk
static constexpr int BSH  = 8;                // 256 nodes per bucket
static constexpr int NBkt = (Nn + 255) >> 8;  // 391 buckets
static constexpr int HPAD = ((NP * NBkt + 3) & ~3);  // hist ints, 16B-padded

// ---------------- P1: per-chunk bucket histogram (LDS) ----------------
__global__ __launch_bounds__(256) void k_part1(const int* __restrict__ dst,
                                               int* __restrict__ hist) {
    __shared__ int h[NBkt];
    int tid = threadIdx.x;
    for (int b = tid; b < NBkt; b += 256) h[b] = 0;
    __syncthreads();
    int e0 = blockIdx.x * CH;
    for (int i = tid; i < CH; i += 256)
        atomicAdd(&h[dst[e0 + i] >> BSH], 1);
    __syncthreads();
    for (int b = tid; b < NBkt; b += 256)
        hist[blockIdx.x * NBkt + b] = h[b];
}

// ---------------- S1: bucket totals ----------------
__global__ __launch_bounds__(256) void k_sum(const int* __restrict__ hist,
                                             int* __restrict__ tot) {
    __shared__ int sh[256];
    int b = blockIdx.x, tid = threadIdx.x;
    sh[tid] = (tid < NP) ? hist[tid * NBkt + b] : 0;
    __syncthreads();
    for (int off = 128; off; off >>= 1) {
        if (tid < off) sh[tid] += sh[tid + off];
        __syncthreads();
    }
    if (tid == 0) tot[b] = sh[0];
}

// ---------------- S2: exclusive scan of bucket totals + zero stats ----------------
__global__ __launch_bounds__(512) void k_base(const int* __restrict__ tot,
                                              int* __restrict__ base, double* stats) {
    __shared__ int sh[512];
    int t = threadIdx.x;
    if (t < 256) stats[t] = 0.0;          // stats1+stats2
    int v = (t < NBkt) ? tot[t] : 0;
    sh[t] = v;
    __syncthreads();
    for (int off = 1; off < 512; off <<= 1) {
        int a = (t >= off) ? sh[t - off] : 0;
        __syncthreads();
        sh[t] += a;
        __syncthreads();
    }
    if (t < NBkt) base[t] = sh[t] - v;    // exclusive
    if (t == 0) base[NBkt] = Ne;
}

// ---------------- S3: per-bucket scan over wgs -> run offsets (in place) ----------------
__global__ __launch_bounds__(256) void k_off(int* __restrict__ hist,
                                             const int* __restrict__ base) {
    __shared__ int sh[256];
    int b = blockIdx.x, t = threadIdx.x;
    int v = (t < NP) ? hist[t * NBkt + b] : 0;
    sh[t] = v;
    __syncthreads();
    for (int off = 1; off < 256; off <<= 1) {
        int a = (t >= off) ? sh[t - off] : 0;
        __syncthreads();
        sh[t] += a;
        __syncthreads();
    }
    if (t < NP) hist[t * NBkt + b] = base[b] + sh[t] - v;   // exclusive + base
}

// ---------------- P3: partition-scatter into bucket runs (LDS cursors) ----------------
__global__ __launch_bounds__(256) void k_part2(const int* __restrict__ src,
                                               const int* __restrict__ dst,
                                               const int* __restrict__ hist,
                                               int* __restrict__ bucketed) {
    __shared__ int cur[NBkt];
    int tid = threadIdx.x;
    for (int b = tid; b < NBkt; b += 256) cur[b] = hist[blockIdx.x * NBkt + b];
    __syncthreads();
    int e0 = blockIdx.x * CH;
    for (int i = tid; i < CH; i += 256) {
        int e = e0 + i;
        int s = src[e], d = dst[e];
        int pos = atomicAdd(&cur[d >> BSH], 1);
        bucketed[pos] = s | ((d & 255) << 17);   // src<2^17, dst_local<2^8
    }
}

// ---------------- P4: per-bucket CSR fill + row_ptr + dinv (all LDS-local) ----------------
__global__ __launch_bounds__(256) void k_bfill(const int* __restrict__ base,
                                               const int* __restrict__ bucketed,
                                               int* __restrict__ csr_src,
                                               int* __restrict__ row_ptr,
                                               float* __restrict__ dinv) {
    __shared__ int ncnt[256];
    __shared__ int sc[256];
    __shared__ int cur[256];
    int b = blockIdx.x, tid = threadIdx.x;
    int e0 = base[b], e1 = base[b + 1];
    ncnt[tid] = 0;
    __syncthreads();
    for (int i = e0 + tid; i < e1; i += 256)
        atomicAdd(&ncnt[bucketed[i] >> 17], 1);
    __syncthreads();
    int v = ncnt[tid];
    sc[tid] = v;
    __syncthreads();
    for (int off = 1; off < 256; off <<= 1) {
        int a = (tid >= off) ? sc[tid - off] : 0;
        __syncthreads();
        sc[tid] += a;
        __syncthreads();
    }
    int excl = sc[tid] - v;
    int node = (b << BSH) + tid;
    if (node < Nn) {
        int r = e0 + excl;
        row_ptr[node] = r;
        cur[tid] = r;
        dinv[node] = rsqrtf(1.0f + (float)v);
    }
    if (b == NBkt - 1 && tid == 0) row_ptr[Nn] = Ne;
    __syncthreads();
    for (int i = e0 + tid; i < e1; i += 256) {
        int p = bucketed[i];
        int pos = atomicAdd(&cur[p >> 17], 1);
        csr_src[pos] = p & 0x1FFFF;
    }
}

// ---------------- pad + pre-scale: xp[n] = x[n] * dinv[n], 22->24 floats ----------------
__global__ void k_pad(const float* __restrict__ x, const float* __restrict__ dinv,
                      float* __restrict__ xp) {
    int idx = blockIdx.x * blockDim.x + threadIdx.x;   // Nn*6 float4s
    if (idx >= Nn * 6) return;
    int n = idx / 6, q = idx - n * 6;
    float di = dinv[n];
    float4 v;
    int f0 = q * 4;
    const float* xr = x + n * Fin;
    v.x = (f0 + 0 < Fin) ? xr[f0 + 0] * di : 0.f;
    v.y = (f0 + 1 < Fin) ? xr[f0 + 1] * di : 0.f;
    v.z = (f0 + 2 < Fin) ? xr[f0 + 2] * di : 0.f;
    v.w = (f0 + 3 < Fin) ? xr[f0 + 3] * di : 0.f;
    ((float4*)xp)[idx] = v;
}

// ---------------- gather1: aggx[n] = dinv[n] * (xp'[n] + sum_e xp'[src])  (24 floats) ----------------
__global__ __launch_bounds__(256) void k_gather1(const int* __restrict__ row_ptr,
                                                 const int* __restrict__ csr_src,
                                                 const float* __restrict__ dinv,
                                                 const float* __restrict__ xp,
                                                 float* __restrict__ outp) {
    int idx = blockIdx.x * blockDim.x + threadIdx.x;   // Nn*6 threads
    if (idx >= Nn * 6) return;
    int n = idx / 6, q = idx - n * 6;
    const float4* h4 = (const float4*)xp;
    float di = dinv[n];
    float4 a0 = h4[n * 6 + q];     // self term (xp already scaled by dinv[n])
    float4 a1 = make_float4(0.f, 0.f, 0.f, 0.f);
    float4 a2 = make_float4(0.f, 0.f, 0.f, 0.f);
    float4 a3 = make_float4(0.f, 0.f, 0.f, 0.f);
    int e = row_ptr[n], e1 = row_ptr[n + 1];
    for (; e + 3 < e1; e += 4) {
        int s0 = csr_src[e], s1 = csr_src[e + 1], s2 = csr_src[e + 2], s3 = csr_src[e + 3];
        float4 v0 = h4[s0 * 6 + q];
        float4 v1 = h4[s1 * 6 + q];
        float4 v2 = h4[s2 * 6 + q];
        float4 v3 = h4[s3 * 6 + q];
        a0.x += v0.x; a0.y += v0.y; a0.z += v0.z; a0.w += v0.w;
        a1.x += v1.x; a1.y += v1.y; a1.z += v1.z; a1.w += v1.w;
        a2.x += v2.x; a2.y += v2.y; a2.z += v2.z; a2.w += v2.w;
        a3.x += v3.x; a3.y += v3.y; a3.z += v3.z; a3.w += v3.w;
    }
    for (; e < e1; e++) {
        int s = csr_src[e];
        float4 vv = h4[s * 6 + q];
        a0.x += vv.x; a0.y += vv.y; a0.z += vv.z; a0.w += vv.w;
    }
    float4 r;
    r.x = (a0.x + a1.x + a2.x + a3.x) * di;
    r.y = (a0.y + a1.y + a2.y + a3.y) * di;
    r.z = (a0.z + a1.z + a2.z + a3.z) * di;
    r.w = (a0.w + a1.w + a2.w + a3.w) * di;
    ((float4*)outp)[n * 6 + q] = r;
}

// ---------------- GEMM1: aggx[N,24(22)] @ W1[64,22]^T + b1 -> h1[N,64] ----------------
__global__ __launch_bounds__(256) void k_gemm1(const float* __restrict__ aggx,
                                               const float* __restrict__ W1,
                                               const float* __restrict__ b1,
                                               float* __restrict__ out) {
    __shared__ float Wl[64 * 23];
    __shared__ float Xl[4][24];
    int tid = threadIdx.x;
    for (int i = tid; i < 64 * Fin; i += 256) {
        int o = i / Fin, k = i % Fin;
        Wl[o * 23 + k] = W1[i];
    }
    int f = tid & 63, ln = tid >> 6;
    float bf = b1[f];
    for (int base = blockIdx.x * 4; base < Nn; base += gridDim.x * 4) {
        __syncthreads();
        if (tid < 24) {
            int r = tid / 6, q = tid - (tid / 6) * 6;
            if (base + r < Nn)
                *((float4*)&Xl[r][q * 4]) = ((const float4*)aggx)[(base + r) * 6 + q];
        }
        __syncthreads();
        int n = base + ln;
        if (n < Nn) {
            float s = bf;
            #pragma unroll
            for (int k = 0; k < Fin; k++) s += Xl[ln][k] * Wl[f * 23 + k];
            out[n * 64 + f] = s;
        }
    }
}

// ---------------- BN stats: per-feature sum & sumsq (double accum) ----------------
__global__ __launch_bounds__(256) void k_bnstats(const float* __restrict__ a, double* stats) {
    __shared__ float ssum[256], ssq[256];
    int tid = threadIdx.x;
    int f = tid & 63, ln = tid >> 6;
    float s = 0.f, q = 0.f;
    for (int n = blockIdx.x * 4 + ln; n < Nn; n += gridDim.x * 4) {
        float v = a[n * 64 + f];
        s += v;
        q += v * v;
    }
    ssum[tid] = s; ssq[tid] = q;
    __syncthreads();
    if (tid < 64) {
        s = ssum[tid] + ssum[tid + 64] + ssum[tid + 128] + ssum[tid + 192];
        q = ssq[tid] + ssq[tid + 64] + ssq[tid + 128] + ssq[tid + 192];
        atomicAdd(&stats[f], (double)s);
        atomicAdd(&stats[64 + f], (double)q);
    }
}

// ---------------- GEMM2, fused BN1+ReLU on load, epilogue * dinv[n] ----------------
__global__ __launch_bounds__(256) void k_gemm2(const float* __restrict__ xin,
                                               const float* __restrict__ W2,
                                               const double* __restrict__ stats,
                                               const float* __restrict__ g,
                                               const float* __restrict__ be,
                                               const float* __restrict__ dinv,
                                               float* __restrict__ out) {
    __shared__ float Wl[64 * 65];
    __shared__ float Xl[4][64];
    int tid = threadIdx.x;
    for (int i = tid; i < 64 * 64; i += 256) {
        int o = i >> 6, k = i & 63;
        Wl[o * 65 + k] = W2[i];
    }
    int f = tid & 63, ln = tid >> 6;
    double mu = stats[f] / (double)Nn;
    double var = stats[64 + f] / (double)Nn - mu * mu;
    float sc = rsqrtf((float)var + EPSf) * g[f];
    float muf = (float)mu;
    float bef = be[f];
    for (int base = blockIdx.x * 4; base < Nn; base += gridDim.x * 4) {
        __syncthreads();
        int n = base + ln;
        if (n < Nn) {
            float v = (xin[n * 64 + f] - muf) * sc + bef;
            Xl[ln][f] = v > 0.f ? v : 0.f;
        }
        __syncthreads();
        if (n < Nn) {
            float s = 0.f;
            #pragma unroll
            for (int k = 0; k < 64; k++) s += Xl[ln][k] * Wl[f * 65 + k];
            out[n * 64 + f] = s * dinv[n];   // pre-scale row for src-only gather
        }
    }
}

// ---------------- gather2: out[n] = dinv[n]*(h'[n] + sum_e h'[src]) + b  (64 floats) ----------------
__global__ __launch_bounds__(256) void k_gather2(const int* __restrict__ row_ptr,
                                                 const int* __restrict__ csr_src,
                                                 const float* __restrict__ dinv,
                                                 const float* __restrict__ h,
                                                 const float* __restrict__ bias,
                                                 float* __restrict__ out) {
    int idx = blockIdx.x * blockDim.x + threadIdx.x;   // Nn*16 threads
    if (idx >= Nn * 16) return;
    int n = idx >> 4, q = idx & 15;
    const float4* h4 = (const float4*)h;
    float di = dinv[n];
    float4 bv = ((const float4*)bias)[q];
    float4 a0 = h4[n * 16 + q];    // self term (h already scaled by dinv[n])
    float4 a1 = make_float4(0.f, 0.f, 0.f, 0.f);
    float4 a2 = make_float4(0.f, 0.f, 0.f, 0.f);
    float4 a3 = make_float4(0.f, 0.f, 0.f, 0.f);
    int e = row_ptr[n], e1 = row_ptr[n + 1];
    for (; e + 3 < e1; e += 4) {
        int s0 = csr_src[e], s1 = csr_src[e + 1], s2 = csr_src[e + 2], s3 = csr_src[e + 3];
        float4 v0 = h4[s0 * 16 + q];
        float4 v1 = h4[s1 * 16 + q];
        float4 v2 = h4[s2 * 16 + q];
        float4 v3 = h4[s3 * 16 + q];
        a0.x += v0.x; a0.y += v0.y; a0.z += v0.z; a0.w += v0.w;
        a1.x += v1.x; a1.y += v1.y; a1.z += v1.z; a1.w += v1.w;
        a2.x += v2.x; a2.y += v2.y; a2.z += v2.z; a2.w += v2.w;
        a3.x += v3.x; a3.y += v3.y; a3.z += v3.z; a3.w += v3.w;
    }
    for (; e < e1; e++) {
        int s = csr_src[e];
        float4 vv = h4[s * 16 + q];
        a0.x += vv.x; a0.y += vv.y; a0.z += vv.z; a0.w += vv.w;
    }
    float4 r;
    r.x = (a0.x + a1.x + a2.x + a3.x) * di + bv.x;
    r.y = (a0.y + a1.y + a2.y + a3.y) * di + bv.y;
    r.z = (a0.z + a1.z + a2.z + a3.z) * di + bv.z;
    r.w = (a0.w + a1.w + a2.w + a3.w) * di + bv.w;
    ((float4*)out)[n * 16 + q] = r;
}

// ---------------- pool + BN2 + ReLU + MLP, one block (64 thr) per graph ----------------
__global__ __launch_bounds__(64) void k_poolmlp(const float* __restrict__ a,
                                                const int* __restrict__ batch,
                                                const double* __restrict__ stats,
                                                const float* __restrict__ g,
                                                const float* __restrict__ be,
                                                const float* __restrict__ fcw1,
                                                const float* __restrict__ fcb1,
                                                const float* __restrict__ fcw2,
                                                const float* __restrict__ fcb2,
                                                float* __restrict__ out) {
    __shared__ float p[64];
    int gidx = blockIdx.x;
    int tid = threadIdx.x;   // feature
    int lo = 0, hi = Nn;
    while (lo < hi) { int m = (lo + hi) >> 1; if (batch[m] < gidx) lo = m + 1; else hi = m; }
    int start = lo;
    hi = Nn;
    while (lo < hi) { int m = (lo + hi) >> 1; if (batch[m] < gidx + 1) lo = m + 1; else hi = m; }
    int end = lo;
    double mu = stats[tid] / (double)Nn;
    double var = stats[64 + tid] / (double)Nn - mu * mu;
    float sc = rsqrtf((float)var + EPSf) * g[tid];
    float muf = (float)mu;
    float bef = be[tid];
    float s = 0.f;
    for (int n = start; n < end; n++) {
        float v = (a[n * 64 + tid] - muf) * sc + bef;
        s += v > 0.f ? v : 0.f;
    }
    int cnt = end - start;
    float c = cnt < 1 ? 1.f : (float)cnt;
    p[tid] = s / c;
    __syncthreads();
    float w = 0.f;
    if (tid < 32) {
        float z = fcb1[tid];
        #pragma unroll
        for (int k = 0; k < 64; k++) z += p[k] * fcw1[tid * 64 + k];
        z = z > 0.f ? z : 0.f;
        w = z * fcw2[tid];
    }
    for (int off = 16; off; off >>= 1) w += __shfl_down(w, off);
    if (tid == 0) out[gidx] = w + fcb2[0];
}

extern "C" void kernel_launch(void* const* d_in, const int* in_sizes, int n_in,
                              void* d_out, int out_size, void* d_ws, size_t ws_size,
                              hipStream_t stream) {
    const float* x    = (const float*)d_in[0];
    const int* ei     = (const int*)d_in[1];
    const int* src    = ei;
    const int* dst    = ei + Ne;
    const int* batch  = (const int*)d_in[2];
    const float* W1   = (const float*)d_in[3];
    const float* b1   = (const float*)d_in[4];
    const float* g1   = (const float*)d_in[5];
    const float* be1  = (const float*)d_in[6];
    const float* W2   = (const float*)d_in[7];
    const float* b2   = (const float*)d_in[8];
    const float* g2   = (const float*)d_in[9];
    const float* be2  = (const float*)d_in[10];
    const float* fcw1 = (const float*)d_in[11];
    const float* fcb1 = (const float*)d_in[12];
    const float* fcw2 = (const float*)d_in[13];
    const float* fcb2 = (const float*)d_in[14];
    float* out = (float*)d_out;

    // workspace layout (16B-aligned blocks)
    double* stats1   = (double*)d_ws;             // 256 doubles (stats1+stats2)
    double* stats2   = stats1 + 128;
    int*    hist     = (int*)(stats1 + 256);      // HPAD (= NP*NBkt padded)
    int*    tot      = hist + HPAD;               // 392
    int*    base     = tot + 392;                 // 392 (NBkt+1 used)
    int*    bucketed = base + 392;                // Ne packed {src, dst_local}
    int*    csr_src  = bucketed + Ne;             // Ne
    int*    row_ptr  = csr_src + Ne;              // Nn+1 (padded to 100004)
    float*  dinv     = (float*)(row_ptr + 100004);// Nn
    float*  bufA     = dinv + Nn;                 // N*64: xp -> h1 -> agg2
    float*  bufB     = bufA + Nn * 64;            // N*64: aggx -> h2'

    // ---- CSR build: LDS-staged two-pass partition ----
    k_part1<<<NP, 256, 0, stream>>>(dst, hist);
    k_sum<<<NBkt, 256, 0, stream>>>(hist, tot);
    k_base<<<1, 512, 0, stream>>>(tot, base, stats1);
    k_off<<<NBkt, 256, 0, stream>>>(hist, base);
    k_part2<<<NP, 256, 0, stream>>>(src, dst, hist, bucketed);
    k_bfill<<<NBkt, 256, 0, stream>>>(base, bucketed, csr_src, row_ptr, dinv);

    // ---- pre-scaled pad ----
    k_pad<<<(Nn * 6 + 255) / 256, 256, 0, stream>>>(x, dinv, bufA);

    // ---- layer 1: gather pre-scaled x (24f rows), then GEMM ----
    k_gather1<<<(Nn * 6 + 255) / 256, 256, 0, stream>>>(row_ptr, csr_src, dinv, bufA, bufB);
    k_gemm1<<<1024, 256, 0, stream>>>(bufB, W1, b1, bufA);
    k_bnstats<<<512, 256, 0, stream>>>(bufA, stats1);

    // ---- layer 2: GEMM (BN1+ReLU fused, *dinv epilogue), then gather ----
    k_gemm2<<<2048, 256, 0, stream>>>(bufA, W2, stats1, g1, be1, dinv, bufB);
    k_gather2<<<(Nn * 16 + 255) / 256, 256, 0, stream>>>(row_ptr, csr_src, dinv, bufB, b2, bufA);
    k_bnstats<<<512, 256, 0, stream>>>(bufA, stats2);

    // ---- pool + BN2 + ReLU + MLP ----
    k_poolmlp<<<Gg, 64, 0, stream>>>(bufA, batch, stats2, g2, be2,
                                     fcw1, fcb1, fcw2, fcb2, out);
}

// Round 15
// 401.229 us; speedup vs baseline: 1.3072x; 1.0029x over previous
//
#include <hip/hip_runtime.h>

static constexpr int Nn  = 100000;
static constexpr int Ne  = 1600000;
static constexpr int Gg  = 2048;
static constexpr int Fin = 22;
static constexpr float EPSf = 1e-5f;

static constexpr int NP   = 250;              // partition workgroups
static constexpr int CH   = Ne / NP;          // 6400 edges per chunk
static constexpr int BSH  = 8;                // 256 nodes per bucket
static constexpr int NBkt = (Nn + 255) >> 8;  // 391 buckets
static constexpr int HPAD = ((NP * NBkt + 3) & ~3);  // hist ints, 16B-padded

// ---------------- P1: per-chunk bucket histogram (LDS) ----------------
__global__ __launch_bounds__(256) void k_part1(const int* __restrict__ dst,
                                               int* __restrict__ hist) {
    __shared__ int h[NBkt];
    int tid = threadIdx.x;
    for (int b = tid; b < NBkt; b += 256) h[b] = 0;
    __syncthreads();
    int e0 = blockIdx.x * CH;
    for (int i = tid; i < CH; i += 256)
        atomicAdd(&h[dst[e0 + i] >> BSH], 1);
    __syncthreads();
    for (int b = tid; b < NBkt; b += 256)
        hist[blockIdx.x * NBkt + b] = h[b];
}

// ---------------- S1: bucket totals ----------------
__global__ __launch_bounds__(256) void k_sum(const int* __restrict__ hist,
                                             int* __restrict__ tot) {
    __shared__ int sh[256];
    int b = blockIdx.x, tid = threadIdx.x;
    sh[tid] = (tid < NP) ? hist[tid * NBkt + b] : 0;
    __syncthreads();
    for (int off = 128; off; off >>= 1) {
        if (tid < off) sh[tid] += sh[tid + off];
        __syncthreads();
    }
    if (tid == 0) tot[b] = sh[0];
}

// ---------------- S2: exclusive scan of bucket totals + zero stats ----------------
__global__ __launch_bounds__(512) void k_base(const int* __restrict__ tot,
                                              int* __restrict__ base, double* stats) {
    __shared__ int sh[512];
    int t = threadIdx.x;
    if (t < 256) stats[t] = 0.0;          // stats1+stats2
    int v = (t < NBkt) ? tot[t] : 0;
    sh[t] = v;
    __syncthreads();
    for (int off = 1; off < 512; off <<= 1) {
        int a = (t >= off) ? sh[t - off] : 0;
        __syncthreads();
        sh[t] += a;
        __syncthreads();
    }
    if (t < NBkt) base[t] = sh[t] - v;    // exclusive
    if (t == 0) base[NBkt] = Ne;
}

// ---------------- S3: per-bucket scan over wgs -> run offsets (in place) ----------------
__global__ __launch_bounds__(256) void k_off(int* __restrict__ hist,
                                             const int* __restrict__ base) {
    __shared__ int sh[256];
    int b = blockIdx.x, t = threadIdx.x;
    int v = (t < NP) ? hist[t * NBkt + b] : 0;
    sh[t] = v;
    __syncthreads();
    for (int off = 1; off < 256; off <<= 1) {
        int a = (t >= off) ? sh[t - off] : 0;
        __syncthreads();
        sh[t] += a;
        __syncthreads();
    }
    if (t < NP) hist[t * NBkt + b] = base[b] + sh[t] - v;   // exclusive + base
}

// ---------------- P3: partition-scatter into bucket runs (LDS cursors) ----------------
__global__ __launch_bounds__(256) void k_part2(const int* __restrict__ src,
                                               const int* __restrict__ dst,
                                               const int* __restrict__ hist,
                                               int* __restrict__ bucketed) {
    __shared__ int cur[NBkt];
    int tid = threadIdx.x;
    for (int b = tid; b < NBkt; b += 256) cur[b] = hist[blockIdx.x * NBkt + b];
    __syncthreads();
    int e0 = blockIdx.x * CH;
    for (int i = tid; i < CH; i += 256) {
        int e = e0 + i;
        int s = src[e], d = dst[e];
        int pos = atomicAdd(&cur[d >> BSH], 1);
        bucketed[pos] = s | ((d & 255) << 17);   // src<2^17, dst_local<2^8
    }
}

// ---------------- P4: per-bucket CSR fill + row_ptr + dinv (all LDS-local) ----------------
__global__ __launch_bounds__(256) void k_bfill(const int* __restrict__ base,
                                               const int* __restrict__ bucketed,
                                               int* __restrict__ csr_src,
                                               int* __restrict__ row_ptr,
                                               float* __restrict__ dinv) {
    __shared__ int ncnt[256];
    __shared__ int sc[256];
    __shared__ int cur[256];
    int b = blockIdx.x, tid = threadIdx.x;
    int e0 = base[b], e1 = base[b + 1];
    ncnt[tid] = 0;
    __syncthreads();
    for (int i = e0 + tid; i < e1; i += 256)
        atomicAdd(&ncnt[bucketed[i] >> 17], 1);
    __syncthreads();
    int v = ncnt[tid];
    sc[tid] = v;
    __syncthreads();
    for (int off = 1; off < 256; off <<= 1) {
        int a = (tid >= off) ? sc[tid - off] : 0;
        __syncthreads();
        sc[tid] += a;
        __syncthreads();
    }
    int excl = sc[tid] - v;
    int node = (b << BSH) + tid;
    if (node < Nn) {
        int r = e0 + excl;
        row_ptr[node] = r;
        cur[tid] = r;
        dinv[node] = rsqrtf(1.0f + (float)v);
    }
    if (b == NBkt - 1 && tid == 0) row_ptr[Nn] = Ne;
    __syncthreads();
    for (int i = e0 + tid; i < e1; i += 256) {
        int p = bucketed[i];
        int pos = atomicAdd(&cur[p >> 17], 1);
        csr_src[pos] = p & 0x1FFFF;
    }
}

// ---------------- pad + pre-scale: xp[n] = x[n]*dinv[n], 22 -> 32 floats (128B rows) ----------------
__global__ void k_pad(const float* __restrict__ x, const float* __restrict__ dinv,
                      float* __restrict__ xp) {
    int idx = blockIdx.x * blockDim.x + threadIdx.x;   // Nn*8 float4s
    if (idx >= Nn * 8) return;
    int n = idx >> 3, q = idx & 7;
    float di = dinv[n];
    float4 v = make_float4(0.f, 0.f, 0.f, 0.f);
    int f0 = q * 4;
    const float* xr = x + n * Fin;
    if (f0 + 0 < Fin) v.x = xr[f0 + 0] * di;
    if (f0 + 1 < Fin) v.y = xr[f0 + 1] * di;
    if (f0 + 2 < Fin) v.z = xr[f0 + 2] * di;
    if (f0 + 3 < Fin) v.w = xr[f0 + 3] * di;
    ((float4*)xp)[idx] = v;
}

// ---------------- gather1: aggx[n] = dinv[n]*(xp'[n] + sum_e xp'[src])  (reads 32f rows, writes 24f) ----------------
__global__ __launch_bounds__(256) void k_gather1(const int* __restrict__ row_ptr,
                                                 const int* __restrict__ csr_src,
                                                 const float* __restrict__ dinv,
                                                 const float* __restrict__ xp,
                                                 float* __restrict__ outp) {
    int idx = blockIdx.x * blockDim.x + threadIdx.x;   // Nn*6 threads
    if (idx >= Nn * 6) return;
    int n = idx / 6, q = idx - n * 6;
    const float4* h4 = (const float4*)xp;
    float di = dinv[n];
    float4 a0 = h4[n * 8 + q];     // self term (xp already scaled by dinv[n])
    float4 a1 = make_float4(0.f, 0.f, 0.f, 0.f);
    float4 a2 = make_float4(0.f, 0.f, 0.f, 0.f);
    float4 a3 = make_float4(0.f, 0.f, 0.f, 0.f);
    int e = row_ptr[n], e1 = row_ptr[n + 1];
    for (; e + 3 < e1; e += 4) {
        int s0 = csr_src[e], s1 = csr_src[e + 1], s2 = csr_src[e + 2], s3 = csr_src[e + 3];
        float4 v0 = h4[s0 * 8 + q];
        float4 v1 = h4[s1 * 8 + q];
        float4 v2 = h4[s2 * 8 + q];
        float4 v3 = h4[s3 * 8 + q];
        a0.x += v0.x; a0.y += v0.y; a0.z += v0.z; a0.w += v0.w;
        a1.x += v1.x; a1.y += v1.y; a1.z += v1.z; a1.w += v1.w;
        a2.x += v2.x; a2.y += v2.y; a2.z += v2.z; a2.w += v2.w;
        a3.x += v3.x; a3.y += v3.y; a3.z += v3.z; a3.w += v3.w;
    }
    for (; e < e1; e++) {
        int s = csr_src[e];
        float4 vv = h4[s * 8 + q];
        a0.x += vv.x; a0.y += vv.y; a0.z += vv.z; a0.w += vv.w;
    }
    float4 r;
    r.x = (a0.x + a1.x + a2.x + a3.x) * di;
    r.y = (a0.y + a1.y + a2.y + a3.y) * di;
    r.z = (a0.z + a1.z + a2.z + a3.z) * di;
    r.w = (a0.w + a1.w + a2.w + a3.w) * di;
    ((float4*)outp)[n * 6 + q] = r;
}

// ---------------- GEMM1 + fused BN1 stats: h1 = aggx@W1^T + b1, stats += (sum, sumsq) ----------------
__global__ __launch_bounds__(256) void k_gemm1(const float* __restrict__ aggx,
                                               const float* __restrict__ W1,
                                               const float* __restrict__ b1,
                                               float* __restrict__ out,
                                               double* stats) {
    __shared__ float Wl[64 * 23];
    __shared__ float Xl[4][24];
    __shared__ float r1[256], r2[256];
    int tid = threadIdx.x;
    for (int i = tid; i < 64 * Fin; i += 256) {
        int o = i / Fin, k = i % Fin;
        Wl[o * 23 + k] = W1[i];
    }
    int f = tid & 63, ln = tid >> 6;
    float bf = b1[f];
    float ssum = 0.f, ssq = 0.f;
    for (int base = blockIdx.x * 4; base < Nn; base += gridDim.x * 4) {
        __syncthreads();
        if (tid < 24) {
            int r = tid / 6, q = tid - (tid / 6) * 6;
            if (base + r < Nn)
                *((float4*)&Xl[r][q * 4]) = ((const float4*)aggx)[(base + r) * 6 + q];
        }
        __syncthreads();
        int n = base + ln;
        if (n < Nn) {
            float s = bf;
            #pragma unroll
            for (int k = 0; k < Fin; k++) s += Xl[ln][k] * Wl[f * 23 + k];
            out[n * 64 + f] = s;
            ssum += s;
            ssq += s * s;
        }
    }
    r1[tid] = ssum; r2[tid] = ssq;
    __syncthreads();
    if (tid < 64) {
        float s4 = r1[tid] + r1[tid + 64] + r1[tid + 128] + r1[tid + 192];
        float q4 = r2[tid] + r2[tid + 64] + r2[tid + 128] + r2[tid + 192];
        atomicAdd(&stats[tid], (double)s4);
        atomicAdd(&stats[64 + tid], (double)q4);
    }
}

// ---------------- GEMM2, fused BN1+ReLU on load, epilogue * dinv[n] ----------------
__global__ __launch_bounds__(256) void k_gemm2(const float* __restrict__ xin,
                                               const float* __restrict__ W2,
                                               const double* __restrict__ stats,
                                               const float* __restrict__ g,
                                               const float* __restrict__ be,
                                               const float* __restrict__ dinv,
                                               float* __restrict__ out) {
    __shared__ float Wl[64 * 65];
    __shared__ float Xl[4][64];
    int tid = threadIdx.x;
    for (int i = tid; i < 64 * 64; i += 256) {
        int o = i >> 6, k = i & 63;
        Wl[o * 65 + k] = W2[i];
    }
    int f = tid & 63, ln = tid >> 6;
    double mu = stats[f] / (double)Nn;
    double var = stats[64 + f] / (double)Nn - mu * mu;
    float sc = rsqrtf((float)var + EPSf) * g[f];
    float muf = (float)mu;
    float bef = be[f];
    for (int base = blockIdx.x * 4; base < Nn; base += gridDim.x * 4) {
        __syncthreads();
        int n = base + ln;
        if (n < Nn) {
            float v = (xin[n * 64 + f] - muf) * sc + bef;
            Xl[ln][f] = v > 0.f ? v : 0.f;
        }
        __syncthreads();
        if (n < Nn) {
            float s = 0.f;
            #pragma unroll
            for (int k = 0; k < 64; k++) s += Xl[ln][k] * Wl[f * 65 + k];
            out[n * 64 + f] = s * dinv[n];   // pre-scale row for src-only gather
        }
    }
}

// ---------------- gather2 + fused BN2 stats: out[n]=dinv*(h'[n]+sum h'[src])+b, grid-stride ----------------
__global__ __launch_bounds__(256) void k_gather2(const int* __restrict__ row_ptr,
                                                 const int* __restrict__ csr_src,
                                                 const float* __restrict__ dinv,
                                                 const float* __restrict__ h,
                                                 const float* __restrict__ bias,
                                                 float* __restrict__ out,
                                                 double* stats) {
    __shared__ float ss[64], sq[64];
    int tid = threadIdx.x;
    if (tid < 64) { ss[tid] = 0.f; sq[tid] = 0.f; }
    __syncthreads();
    const float4* h4 = (const float4*)h;
    float st0 = 0.f, st1 = 0.f, st2 = 0.f, st3 = 0.f;
    float sg0 = 0.f, sg1 = 0.f, sg2 = 0.f, sg3 = 0.f;
    for (int idx = blockIdx.x * 256 + tid; idx < Nn * 16; idx += gridDim.x * 256) {
        int n = idx >> 4, q = idx & 15;
        float di = dinv[n];
        float4 bv = ((const float4*)bias)[q];
        float4 a0 = h4[n * 16 + q];    // self term (h already scaled by dinv[n])
        float4 a1 = make_float4(0.f, 0.f, 0.f, 0.f);
        float4 a2 = make_float4(0.f, 0.f, 0.f, 0.f);
        float4 a3 = make_float4(0.f, 0.f, 0.f, 0.f);
        int e = row_ptr[n], e1 = row_ptr[n + 1];
        for (; e + 3 < e1; e += 4) {
            int s0 = csr_src[e], s1 = csr_src[e + 1], s2 = csr_src[e + 2], s3 = csr_src[e + 3];
            float4 v0 = h4[s0 * 16 + q];
            float4 v1 = h4[s1 * 16 + q];
            float4 v2 = h4[s2 * 16 + q];
            float4 v3 = h4[s3 * 16 + q];
            a0.x += v0.x; a0.y += v0.y; a0.z += v0.z; a0.w += v0.w;
            a1.x += v1.x; a1.y += v1.y; a1.z += v1.z; a1.w += v1.w;
            a2.x += v2.x; a2.y += v2.y; a2.z += v2.z; a2.w += v2.w;
            a3.x += v3.x; a3.y += v3.y; a3.z += v3.z; a3.w += v3.w;
        }
        for (; e < e1; e++) {
            int s = csr_src[e];
            float4 vv = h4[s * 16 + q];
            a0.x += vv.x; a0.y += vv.y; a0.z += vv.z; a0.w += vv.w;
        }
        float4 r;
        r.x = (a0.x + a1.x + a2.x + a3.x) * di + bv.x;
        r.y = (a0.y + a1.y + a2.y + a3.y) * di + bv.y;
        r.z = (a0.z + a1.z + a2.z + a3.z) * di + bv.z;
        r.w = (a0.w + a1.w + a2.w + a3.w) * di + bv.w;
        ((float4*)out)[idx] = r;
        st0 += r.x; sg0 += r.x * r.x;
        st1 += r.y; sg1 += r.y * r.y;
        st2 += r.z; sg2 += r.z * r.z;
        st3 += r.w; sg3 += r.w * r.w;
    }
    int q = tid & 15;   // iteration-invariant (stride is a multiple of 16)
    atomicAdd(&ss[q * 4 + 0], st0);
    atomicAdd(&ss[q * 4 + 1], st1);
    atomicAdd(&ss[q * 4 + 2], st2);
    atomicAdd(&ss[q * 4 + 3], st3);
    atomicAdd(&sq[q * 4 + 0], sg0);
    atomicAdd(&sq[q * 4 + 1], sg1);
    atomicAdd(&sq[q * 4 + 2], sg2);
    atomicAdd(&sq[q * 4 + 3], sg3);
    __syncthreads();
    if (tid < 64) {
        atomicAdd(&stats[tid], (double)ss[tid]);
        atomicAdd(&stats[64 + tid], (double)sq[tid]);
    }
}

// ---------------- pool + BN2 + ReLU + MLP, one block (64 thr) per graph ----------------
__global__ __launch_bounds__(64) void k_poolmlp(const float* __restrict__ a,
                                                const int* __restrict__ batch,
                                                const double* __restrict__ stats,
                                                const float* __restrict__ g,
                                                const float* __restrict__ be,
                                                const float* __restrict__ fcw1,
                                                const float* __restrict__ fcb1,
                                                const float* __restrict__ fcw2,
                                                const float* __restrict__ fcb2,
                                                float* __restrict__ out) {
    __shared__ float p[64];
    int gidx = blockIdx.x;
    int tid = threadIdx.x;   // feature
    int lo = 0, hi = Nn;
    while (lo < hi) { int m = (lo + hi) >> 1; if (batch[m] < gidx) lo = m + 1; else hi = m; }
    int start = lo;
    hi = Nn;
    while (lo < hi) { int m = (lo + hi) >> 1; if (batch[m] < gidx + 1) lo = m + 1; else hi = m; }
    int end = lo;
    double mu = stats[tid] / (double)Nn;
    double var = stats[64 + tid] / (double)Nn - mu * mu;
    float sc = rsqrtf((float)var + EPSf) * g[tid];
    float muf = (float)mu;
    float bef = be[tid];
    float s = 0.f;
    for (int n = start; n < end; n++) {
        float v = (a[n * 64 + tid] - muf) * sc + bef;
        s += v > 0.f ? v : 0.f;
    }
    int cnt = end - start;
    float c = cnt < 1 ? 1.f : (float)cnt;
    p[tid] = s / c;
    __syncthreads();
    float w = 0.f;
    if (tid < 32) {
        float z = fcb1[tid];
        #pragma unroll
        for (int k = 0; k < 64; k++) z += p[k] * fcw1[tid * 64 + k];
        z = z > 0.f ? z : 0.f;
        w = z * fcw2[tid];
    }
    for (int off = 16; off; off >>= 1) w += __shfl_down(w, off);
    if (tid == 0) out[gidx] = w + fcb2[0];
}

extern "C" void kernel_launch(void* const* d_in, const int* in_sizes, int n_in,
                              void* d_out, int out_size, void* d_ws, size_t ws_size,
                              hipStream_t stream) {
    const float* x    = (const float*)d_in[0];
    const int* ei     = (const int*)d_in[1];
    const int* src    = ei;
    const int* dst    = ei + Ne;
    const int* batch  = (const int*)d_in[2];
    const float* W1   = (const float*)d_in[3];
    const float* b1   = (const float*)d_in[4];
    const float* g1   = (const float*)d_in[5];
    const float* be1  = (const float*)d_in[6];
    const float* W2   = (const float*)d_in[7];
    const float* b2   = (const float*)d_in[8];
    const float* g2   = (const float*)d_in[9];
    const float* be2  = (const float*)d_in[10];
    const float* fcw1 = (const float*)d_in[11];
    const float* fcb1 = (const float*)d_in[12];
    const float* fcw2 = (const float*)d_in[13];
    const float* fcb2 = (const float*)d_in[14];
    float* out = (float*)d_out;

    // workspace layout (16B-aligned blocks)
    double* stats1   = (double*)d_ws;             // 256 doubles (stats1+stats2)
    double* stats2   = stats1 + 128;
    int*    hist     = (int*)(stats1 + 256);      // HPAD
    int*    tot      = hist + HPAD;               // 392
    int*    base     = tot + 392;                 // 392 (NBkt+1 used)
    int*    bucketed = base + 392;                // Ne packed {src, dst_local}
    int*    csr_src  = bucketed + Ne;             // Ne
    int*    row_ptr  = csr_src + Ne;              // Nn+1 (padded to 100004)
    float*  dinv     = (float*)(row_ptr + 100004);// Nn
    float*  bufA     = dinv + Nn;                 // N*64: xp(32f) -> h1 -> agg2
    float*  bufB     = bufA + Nn * 64;            // N*64: aggx(24f) -> h2'

    // ---- CSR build: LDS-staged two-pass partition ----
    k_part1<<<NP, 256, 0, stream>>>(dst, hist);
    k_sum<<<NBkt, 256, 0, stream>>>(hist, tot);
    k_base<<<1, 512, 0, stream>>>(tot, base, stats1);
    k_off<<<NBkt, 256, 0, stream>>>(hist, base);
    k_part2<<<NP, 256, 0, stream>>>(src, dst, hist, bucketed);
    k_bfill<<<NBkt, 256, 0, stream>>>(base, bucketed, csr_src, row_ptr, dinv);

    // ---- pre-scaled pad (32f aligned rows) ----
    k_pad<<<(Nn * 8 + 255) / 256, 256, 0, stream>>>(x, dinv, bufA);

    // ---- layer 1: gather pre-scaled x, then GEMM (+fused BN1 stats) ----
    k_gather1<<<(Nn * 6 + 255) / 256, 256, 0, stream>>>(row_ptr, csr_src, dinv, bufA, bufB);
    k_gemm1<<<1024, 256, 0, stream>>>(bufB, W1, b1, bufA, stats1);

    // ---- layer 2: GEMM (BN1+ReLU fused, *dinv epilogue), then gather (+fused BN2 stats) ----
    k_gemm2<<<2048, 256, 0, stream>>>(bufA, W2, stats1, g1, be1, dinv, bufB);
    k_gather2<<<1024, 256, 0, stream>>>(row_ptr, csr_src, dinv, bufB, b2, bufA, stats2);

    // ---- pool + BN2 + ReLU + MLP ----
    k_poolmlp<<<Gg, 64, 0, stream>>>(bufA, batch, stats2, g2, be2,
                                     fcw1, fcb1, fcw2, fcb2, out);
}